// Round 3
// baseline (3179.472 us; speedup 1.0000x reference)
//
#include <hip/hip_runtime.h>

#define BB   16
#define SS   8192
#define DD   128
#define HH   256
#define NTOK (BB * SS)
#define TM   32
#define LRATE 0.1f
#define EPSV  1e-5f
#define YSS   260   // padded stride for ys (bank-conflict relief in LN reduce)

__global__ __launch_bounds__(256, 2)
void refine_iter(const float* __restrict__ cur, const float* __restrict__ emb,
                 float* __restrict__ outp,
                 const float* __restrict__ W1,  const float* __restrict__ b1,
                 const float* __restrict__ lng, const float* __restrict__ lnb,
                 const float* __restrict__ W2,  const float* __restrict__ b2,
                 const float* __restrict__ Wg1, const float* __restrict__ bg1,
                 const float* __restrict__ Wg2, const float* __restrict__ bg2)
{
    __shared__ __align__(16) float xs[TM][DD];
    __shared__ __align__(16) float cs[TM][DD];
    __shared__ __align__(16) float ys[TM][YSS];
    __shared__ float red1[TM][8];
    __shared__ float red2[TM][8];
    __shared__ float mu_s[TM];
    __shared__ float rs_s[TM];

    const int t  = threadIdx.x;
    const int g0 = blockIdx.x * TM;

    // ---- stage x tile and context tile ----
    #pragma unroll
    for (int k = 0; k < 4; ++k) {
        const int f = t + k * 256;       // float4 slot in [0,1024)
        const int m = f >> 5;            // token within tile
        const int o = (f & 31) * 4;      // float offset in row
        const int gt = g0 + m;
        const int s  = gt & (SS - 1);
        const int rowbase = gt - s;      // b*S
        const int sp = (s == 0) ? 1 : s - 1;
        const int sn = (s == SS - 1) ? (SS - 2) : s + 1;
        const float4 xv = *(const float4*)(cur + (size_t)gt * DD + o);
        const float4 av = *(const float4*)(cur + (size_t)(rowbase + sp) * DD + o);
        const float4 bv = *(const float4*)(cur + (size_t)(rowbase + sn) * DD + o);
        *(float4*)(&xs[m][o]) = xv;
        float4 cv;
        cv.x = 0.5f * (av.x + bv.x);
        cv.y = 0.5f * (av.y + bv.y);
        cv.z = 0.5f * (av.z + bv.z);
        cv.w = 0.5f * (av.w + bv.w);
        *(float4*)(&cs[m][o]) = cv;
    }
    __syncthreads();

    const int cg  = (t & 63) * 4;   // H-column base, phases A/C
    const int tq  = (t >> 6) * 8;   // token base, phases A/C (8 tokens)
    const int cg2 = (t & 31) * 4;   // D-column base, phases B/D
    const int tq2 = (t >> 5) * 4;   // token base, phases B/D (4 tokens)

    float acc[8][4];

    // ---- Phase A: y1 = xs @ W1 + b1  (TM x 256) ----
    #pragma unroll
    for (int m = 0; m < 8; ++m) {
        acc[m][0] = 0.f; acc[m][1] = 0.f; acc[m][2] = 0.f; acc[m][3] = 0.f;
    }
    for (int d = 0; d < DD; d += 4) {
        const float4 w0 = *(const float4*)(W1 + (size_t)(d + 0) * HH + cg);
        const float4 w1 = *(const float4*)(W1 + (size_t)(d + 1) * HH + cg);
        const float4 w2 = *(const float4*)(W1 + (size_t)(d + 2) * HH + cg);
        const float4 w3 = *(const float4*)(W1 + (size_t)(d + 3) * HH + cg);
        #pragma unroll
        for (int m = 0; m < 8; ++m) {
            const float4 x4 = *(const float4*)(&xs[tq + m][d]);
            acc[m][0] += x4.x * w0.x + x4.y * w1.x + x4.z * w2.x + x4.w * w3.x;
            acc[m][1] += x4.x * w0.y + x4.y * w1.y + x4.z * w2.y + x4.w * w3.y;
            acc[m][2] += x4.x * w0.z + x4.y * w1.z + x4.z * w2.z + x4.w * w3.z;
            acc[m][3] += x4.x * w0.w + x4.y * w1.w + x4.z * w2.w + x4.w * w3.w;
        }
    }
    {
        const float4 bb = *(const float4*)(b1 + cg);
        #pragma unroll
        for (int m = 0; m < 8; ++m) {
            float4 y;
            y.x = acc[m][0] + bb.x; y.y = acc[m][1] + bb.y;
            y.z = acc[m][2] + bb.z; y.w = acc[m][3] + bb.w;
            *(float4*)(&ys[tq + m][cg]) = y;
        }
    }
    __syncthreads();

    // ---- LayerNorm stats over H ----
    {
        const int m = t & 31;
        const int p = t >> 5;
        float s1 = 0.f, s2 = 0.f;
        #pragma unroll
        for (int j = 0; j < 32; j += 4) {
            const float4 v = *(const float4*)(&ys[m][p * 32 + j]);
            s1 += v.x + v.y + v.z + v.w;
            s2 += v.x * v.x + v.y * v.y + v.z * v.z + v.w * v.w;
        }
        red1[m][p] = s1; red2[m][p] = s2;
    }
    __syncthreads();
    if (t < TM) {
        float s1 = 0.f, s2 = 0.f;
        #pragma unroll
        for (int p = 0; p < 8; ++p) { s1 += red1[t][p]; s2 += red2[t][p]; }
        const float mu  = s1 * (1.f / (float)HH);
        const float var = s2 * (1.f / (float)HH) - mu * mu;
        mu_s[t] = mu;
        rs_s[t] = rsqrtf(var + EPSV);
    }
    __syncthreads();

    // ---- normalize + affine + relu, in place ----
    {
        const float4 g4 = *(const float4*)(lng + cg);
        const float4 b4 = *(const float4*)(lnb + cg);
        #pragma unroll
        for (int m = 0; m < 8; ++m) {
            const float mu = mu_s[tq + m];
            const float rs = rs_s[tq + m];
            float4 y = *(float4*)(&ys[tq + m][cg]);
            y.x = fmaxf((y.x - mu) * rs * g4.x + b4.x, 0.f);
            y.y = fmaxf((y.y - mu) * rs * g4.y + b4.y, 0.f);
            y.z = fmaxf((y.z - mu) * rs * g4.z + b4.z, 0.f);
            y.w = fmaxf((y.w - mu) * rs * g4.w + b4.w, 0.f);
            *(float4*)(&ys[tq + m][cg]) = y;
        }
    }
    __syncthreads();

    // ---- Phase B: predicted = h @ W2 + b2 ; err = emb - predicted ----
    float err[4][4];
    {
        float a2[4][4];
        #pragma unroll
        for (int m = 0; m < 4; ++m) {
            a2[m][0] = 0.f; a2[m][1] = 0.f; a2[m][2] = 0.f; a2[m][3] = 0.f;
        }
        for (int k = 0; k < HH; k += 4) {
            const float4 w0 = *(const float4*)(W2 + (size_t)(k + 0) * DD + cg2);
            const float4 w1 = *(const float4*)(W2 + (size_t)(k + 1) * DD + cg2);
            const float4 w2v = *(const float4*)(W2 + (size_t)(k + 2) * DD + cg2);
            const float4 w3 = *(const float4*)(W2 + (size_t)(k + 3) * DD + cg2);
            #pragma unroll
            for (int m = 0; m < 4; ++m) {
                const float4 h4 = *(const float4*)(&ys[tq2 + m][k]);
                a2[m][0] += h4.x * w0.x + h4.y * w1.x + h4.z * w2v.x + h4.w * w3.x;
                a2[m][1] += h4.x * w0.y + h4.y * w1.y + h4.z * w2v.y + h4.w * w3.y;
                a2[m][2] += h4.x * w0.z + h4.y * w1.z + h4.z * w2v.z + h4.w * w3.z;
                a2[m][3] += h4.x * w0.w + h4.y * w1.w + h4.z * w2v.w + h4.w * w3.w;
            }
        }
        const float4 bb = *(const float4*)(b2 + cg2);
        #pragma unroll
        for (int m = 0; m < 4; ++m) {
            const float4 e4 = *(const float4*)(emb + (size_t)(g0 + tq2 + m) * DD + cg2);
            err[m][0] = e4.x - (a2[m][0] + bb.x);
            err[m][1] = e4.y - (a2[m][1] + bb.y);
            err[m][2] = e4.z - (a2[m][2] + bb.z);
            err[m][3] = e4.w - (a2[m][3] + bb.w);
        }
    }
    __syncthreads();   // all reads of h done before ys is overwritten

    // ---- Phase C: r = relu([xs, cs] @ Wg1 + bg1) -> ys ----
    #pragma unroll
    for (int m = 0; m < 8; ++m) {
        acc[m][0] = 0.f; acc[m][1] = 0.f; acc[m][2] = 0.f; acc[m][3] = 0.f;
    }
    for (int d = 0; d < DD; d += 4) {
        const float4 w0 = *(const float4*)(Wg1 + (size_t)(d + 0) * HH + cg);
        const float4 w1 = *(const float4*)(Wg1 + (size_t)(d + 1) * HH + cg);
        const float4 w2 = *(const float4*)(Wg1 + (size_t)(d + 2) * HH + cg);
        const float4 w3 = *(const float4*)(Wg1 + (size_t)(d + 3) * HH + cg);
        #pragma unroll
        for (int m = 0; m < 8; ++m) {
            const float4 x4 = *(const float4*)(&xs[tq + m][d]);
            acc[m][0] += x4.x * w0.x + x4.y * w1.x + x4.z * w2.x + x4.w * w3.x;
            acc[m][1] += x4.x * w0.y + x4.y * w1.y + x4.z * w2.y + x4.w * w3.y;
            acc[m][2] += x4.x * w0.z + x4.y * w1.z + x4.z * w2.z + x4.w * w3.z;
            acc[m][3] += x4.x * w0.w + x4.y * w1.w + x4.z * w2.w + x4.w * w3.w;
        }
    }
    for (int d = 0; d < DD; d += 4) {
        const float4 w0 = *(const float4*)(Wg1 + (size_t)(DD + d + 0) * HH + cg);
        const float4 w1 = *(const float4*)(Wg1 + (size_t)(DD + d + 1) * HH + cg);
        const float4 w2 = *(const float4*)(Wg1 + (size_t)(DD + d + 2) * HH + cg);
        const float4 w3 = *(const float4*)(Wg1 + (size_t)(DD + d + 3) * HH + cg);
        #pragma unroll
        for (int m = 0; m < 8; ++m) {
            const float4 c4 = *(const float4*)(&cs[tq + m][d]);
            acc[m][0] += c4.x * w0.x + c4.y * w1.x + c4.z * w2.x + c4.w * w3.x;
            acc[m][1] += c4.x * w0.y + c4.y * w1.y + c4.z * w2.y + c4.w * w3.y;
            acc[m][2] += c4.x * w0.z + c4.y * w1.z + c4.z * w2.z + c4.w * w3.z;
            acc[m][3] += c4.x * w0.w + c4.y * w1.w + c4.z * w2.w + c4.w * w3.w;
        }
    }
    {
        const float4 bb = *(const float4*)(bg1 + cg);
        #pragma unroll
        for (int m = 0; m < 8; ++m) {
            float4 y;
            y.x = fmaxf(acc[m][0] + bb.x, 0.f);
            y.y = fmaxf(acc[m][1] + bb.y, 0.f);
            y.z = fmaxf(acc[m][2] + bb.z, 0.f);
            y.w = fmaxf(acc[m][3] + bb.w, 0.f);
            *(float4*)(&ys[tq + m][cg]) = y;
        }
    }
    __syncthreads();

    // ---- Phase D: gate = sigmoid(r @ Wg2 + bg2); out = x + LR*gate*err ----
    {
        float a2[4][4];
        #pragma unroll
        for (int m = 0; m < 4; ++m) {
            a2[m][0] = 0.f; a2[m][1] = 0.f; a2[m][2] = 0.f; a2[m][3] = 0.f;
        }
        for (int k = 0; k < HH; k += 4) {
            const float4 w0 = *(const float4*)(Wg2 + (size_t)(k + 0) * DD + cg2);
            const float4 w1 = *(const float4*)(Wg2 + (size_t)(k + 1) * DD + cg2);
            const float4 w2v = *(const float4*)(Wg2 + (size_t)(k + 2) * DD + cg2);
            const float4 w3 = *(const float4*)(Wg2 + (size_t)(k + 3) * DD + cg2);
            #pragma unroll
            for (int m = 0; m < 4; ++m) {
                const float4 r4 = *(const float4*)(&ys[tq2 + m][k]);
                a2[m][0] += r4.x * w0.x + r4.y * w1.x + r4.z * w2v.x + r4.w * w3.x;
                a2[m][1] += r4.x * w0.y + r4.y * w1.y + r4.z * w2v.y + r4.w * w3.y;
                a2[m][2] += r4.x * w0.z + r4.y * w1.z + r4.z * w2v.z + r4.w * w3.z;
                a2[m][3] += r4.x * w0.w + r4.y * w1.w + r4.z * w2v.w + r4.w * w3.w;
            }
        }
        const float4 bb = *(const float4*)(bg2 + cg2);
        #pragma unroll
        for (int m = 0; m < 4; ++m) {
            const float4 x4 = *(const float4*)(&xs[tq2 + m][cg2]);
            float4 o;
            const float z0 = a2[m][0] + bb.x;
            const float z1 = a2[m][1] + bb.y;
            const float z2 = a2[m][2] + bb.z;
            const float z3 = a2[m][3] + bb.w;
            const float gt0 = 1.f / (1.f + __expf(-z0));
            const float gt1 = 1.f / (1.f + __expf(-z1));
            const float gt2 = 1.f / (1.f + __expf(-z2));
            const float gt3 = 1.f / (1.f + __expf(-z3));
            o.x = x4.x + LRATE * gt0 * err[m][0];
            o.y = x4.y + LRATE * gt1 * err[m][1];
            o.z = x4.z + LRATE * gt2 * err[m][2];
            o.w = x4.w + LRATE * gt3 * err[m][3];
            *(float4*)(outp + (size_t)(g0 + tq2 + m) * DD + cg2) = o;
        }
    }
}

extern "C" void kernel_launch(void* const* d_in, const int* in_sizes, int n_in,
                              void* d_out, int out_size, void* d_ws, size_t ws_size,
                              hipStream_t stream) {
    const float* emb = (const float*)d_in[0];
    const float* W1  = (const float*)d_in[1];
    const float* b1  = (const float*)d_in[2];
    const float* lng = (const float*)d_in[3];
    const float* lnb = (const float*)d_in[4];
    const float* W2  = (const float*)d_in[5];
    const float* b2  = (const float*)d_in[6];
    const float* Wg1 = (const float*)d_in[7];
    const float* bg1 = (const float*)d_in[8];
    const float* Wg2 = (const float*)d_in[9];
    const float* bg2 = (const float*)d_in[10];
    float* out = (float*)d_out;
    float* ws  = (float*)d_ws;   // one 64 MB ping buffer

    const dim3 grid(NTOK / TM);
    const dim3 block(256);

    // refined chain: emb -> out -> ws -> out -> ws -> out
    refine_iter<<<grid, block, 0, stream>>>(emb, emb, out, W1, b1, lng, lnb, W2, b2, Wg1, bg1, Wg2, bg2);
    refine_iter<<<grid, block, 0, stream>>>(out, emb, ws,  W1, b1, lng, lnb, W2, b2, Wg1, bg1, Wg2, bg2);
    refine_iter<<<grid, block, 0, stream>>>(ws,  emb, out, W1, b1, lng, lnb, W2, b2, Wg1, bg1, Wg2, bg2);
    refine_iter<<<grid, block, 0, stream>>>(out, emb, ws,  W1, b1, lng, lnb, W2, b2, Wg1, bg1, Wg2, bg2);
    refine_iter<<<grid, block, 0, stream>>>(ws,  emb, out, W1, b1, lng, lnb, W2, b2, Wg1, bg1, Wg2, bg2);
}

// Round 4
// 997.285 us; speedup vs baseline: 3.1881x; 3.1881x over previous
//
#include <hip/hip_runtime.h>

#define BB   16
#define SS   8192
#define DD   128
#define HH   256
#define NTOK (BB * SS)
#define TM   32
#define LRATE 0.1f
#define EPSV  1e-5f

typedef short  bfrag __attribute__((ext_vector_type(8)));   // 8 bf16 = 4 VGPR (MFMA A/B frag)
typedef float  f32x4 __attribute__((ext_vector_type(4)));   // MFMA C/D frag
typedef unsigned short u16;

__device__ __forceinline__ u16 f2bf(float x) {
    unsigned u = __float_as_uint(x);
    unsigned r = (u + 0x7FFFu + ((u >> 16) & 1u)) >> 16;   // RTN-even
    return (u16)r;
}

// ---- weight prep: fp32 [K][N] -> bf16 transposed [N][K] in ws ----
// layout (shorts): W1t[256][128] @0, W2t[128][256] @32768, Wg1t[256][256] @65536, Wg2t[128][256] @131072
__global__ void prep_weights(const float* __restrict__ W1, const float* __restrict__ W2,
                             const float* __restrict__ Wg1, const float* __restrict__ Wg2,
                             u16* __restrict__ wsw) {
    int i = blockIdx.x * 256 + threadIdx.x;   // 0 .. 163839
    if (i < 32768) { int n = i >> 7, k = i & 127; wsw[i] = f2bf(W1[k * 256 + n]); return; }
    i -= 32768;
    if (i < 32768) { int n = i >> 8, k = i & 255; wsw[32768 + n * 256 + k] = f2bf(W2[k * 128 + n]); return; }
    i -= 32768;
    if (i < 65536) { int n = i >> 8, k = i & 255; wsw[65536 + n * 256 + k] = f2bf(Wg1[k * 256 + n]); return; }
    i -= 65536;
    { int n = i >> 8, k = i & 255; wsw[131072 + n * 256 + k] = f2bf(Wg2[k * 128 + n]); }
}

__global__ __launch_bounds__(256, 2)
void refine_iter(const float* __restrict__ cur, const float* __restrict__ emb,
                 float* __restrict__ outp,
                 const u16* __restrict__ w1t, const u16* __restrict__ w2t,
                 const u16* __restrict__ wg1t, const u16* __restrict__ wg2t,
                 const float* __restrict__ b1, const float* __restrict__ lng,
                 const float* __restrict__ lnb, const float* __restrict__ b2,
                 const float* __restrict__ bg1, const float* __restrict__ bg2)
{
    __shared__ u16   Xb[TM][136];     // refined tokens, bf16 (pad 136: 2-way-free frag reads)
    __shared__ u16   Cb[TM][136];     // context, bf16
    __shared__ u16   Hb[TM][264];     // hidden H (phase B input) then R (phase D input)
    __shared__ float Y1f[TM][264];    // phase-A output fp32 for LN (stride%32==8 dwords: conflict-free scatter)
    __shared__ float red1[TM][8];
    __shared__ float red2[TM][8];
    __shared__ float mu_s[TM];
    __shared__ float rs_s[TM];

    const int t    = threadIdx.x;
    const int g0   = blockIdx.x * TM;
    const int lane = t & 63;
    const int wid  = t >> 6;              // 4 waves
    const int l16  = lane & 15;
    const int lk8  = (lane >> 4) * 8;     // k-offset within a 32-chunk
    const int l4   = (lane >> 4) * 4;     // D-frag row offset

    // ---- stage x tile + context tile (fp32 -> bf16) ----
    #pragma unroll
    for (int k = 0; k < 4; ++k) {
        const int f = t + k * 256;
        const int m = f >> 5;
        const int o = (f & 31) * 4;
        const int gt = g0 + m;
        const int s  = gt & (SS - 1);
        const int rowbase = gt - s;
        const int sp = (s == 0) ? 1 : s - 1;
        const int sn = (s == SS - 1) ? (SS - 2) : s + 1;
        const float4 xv = *(const float4*)(cur + (size_t)gt * DD + o);
        const float4 av = *(const float4*)(cur + (size_t)(rowbase + sp) * DD + o);
        const float4 bv = *(const float4*)(cur + (size_t)(rowbase + sn) * DD + o);
        ushort4 xu; xu.x = f2bf(xv.x); xu.y = f2bf(xv.y); xu.z = f2bf(xv.z); xu.w = f2bf(xv.w);
        *(ushort4*)&Xb[m][o] = xu;
        ushort4 cu;
        cu.x = f2bf(0.5f * (av.x + bv.x)); cu.y = f2bf(0.5f * (av.y + bv.y));
        cu.z = f2bf(0.5f * (av.z + bv.z)); cu.w = f2bf(0.5f * (av.w + bv.w));
        *(ushort4*)&Cb[m][o] = cu;
    }
    __syncthreads();

    const f32x4 zf = {0.f, 0.f, 0.f, 0.f};

    // ================= Phase A: Y1 = X @ W1 + b1  (32x256, K=128) =================
    {
        const int n0 = wid * 64;
        f32x4 acc[2][4];
        #pragma unroll
        for (int rt = 0; rt < 2; ++rt)
            #pragma unroll
            for (int ct = 0; ct < 4; ++ct) acc[rt][ct] = zf;
        bfrag afr[2][4];
        #pragma unroll
        for (int rt = 0; rt < 2; ++rt)
            #pragma unroll
            for (int ks = 0; ks < 4; ++ks)
                afr[rt][ks] = *(const bfrag*)&Xb[rt * 16 + l16][ks * 32 + lk8];
        #pragma unroll
        for (int ct = 0; ct < 4; ++ct) {
            const u16* wp = w1t + (size_t)(n0 + ct * 16 + l16) * 128 + lk8;
            #pragma unroll
            for (int ks = 0; ks < 4; ++ks) {
                const bfrag bv = *(const bfrag*)(wp + ks * 32);
                acc[0][ct] = __builtin_amdgcn_mfma_f32_16x16x32_bf16(afr[0][ks], bv, acc[0][ct], 0, 0, 0);
                acc[1][ct] = __builtin_amdgcn_mfma_f32_16x16x32_bf16(afr[1][ks], bv, acc[1][ct], 0, 0, 0);
            }
        }
        #pragma unroll
        for (int ct = 0; ct < 4; ++ct) {
            const float bb = b1[n0 + ct * 16 + l16];
            #pragma unroll
            for (int rt = 0; rt < 2; ++rt)
                #pragma unroll
                for (int r = 0; r < 4; ++r)
                    Y1f[rt * 16 + l4 + r][n0 + ct * 16 + l16] = acc[rt][ct][r] + bb;
        }
    }
    __syncthreads();

    // ================= LayerNorm + relu -> Hb (bf16) =================
    {
        const int m = t >> 3;
        const int base = (t & 7) * 32;
        float s1 = 0.f, s2 = 0.f;
        #pragma unroll
        for (int j = 0; j < 8; ++j) {
            const float4 v = *(const float4*)&Y1f[m][base + j * 4];
            s1 += v.x + v.y + v.z + v.w;
            s2 += v.x * v.x + v.y * v.y + v.z * v.z + v.w * v.w;
        }
        red1[m][t & 7] = s1; red2[m][t & 7] = s2;
    }
    __syncthreads();
    if (t < TM) {
        float s1 = 0.f, s2 = 0.f;
        #pragma unroll
        for (int p = 0; p < 8; ++p) { s1 += red1[t][p]; s2 += red2[t][p]; }
        const float mu  = s1 * (1.f / (float)HH);
        const float var = s2 * (1.f / (float)HH) - mu * mu;
        mu_s[t] = mu;
        rs_s[t] = rsqrtf(var + EPSV);
    }
    __syncthreads();
    {
        const int m = t >> 3;
        const int base = (t & 7) * 32;
        const float mu = mu_s[m], rs = rs_s[m];
        #pragma unroll
        for (int j = 0; j < 8; ++j) {
            const float4 v  = *(const float4*)&Y1f[m][base + j * 4];
            const float4 g4 = *(const float4*)(lng + base + j * 4);
            const float4 b4 = *(const float4*)(lnb + base + j * 4);
            ushort4 h;
            h.x = f2bf(fmaxf((v.x - mu) * rs * g4.x + b4.x, 0.f));
            h.y = f2bf(fmaxf((v.y - mu) * rs * g4.y + b4.y, 0.f));
            h.z = f2bf(fmaxf((v.z - mu) * rs * g4.z + b4.z, 0.f));
            h.w = f2bf(fmaxf((v.w - mu) * rs * g4.w + b4.w, 0.f));
            *(ushort4*)&Hb[m][base + j * 4] = h;
        }
    }
    __syncthreads();

    // ================= Phase B: P = H @ W2 + b2 ; err = emb - P  (32x128, K=256) =================
    float errv[2][2][4];
    {
        const int n0 = wid * 32;
        f32x4 acc[2][2];
        acc[0][0] = zf; acc[0][1] = zf; acc[1][0] = zf; acc[1][1] = zf;
        #pragma unroll
        for (int ks = 0; ks < 8; ++ks) {
            const bfrag a0 = *(const bfrag*)&Hb[l16][ks * 32 + lk8];
            const bfrag a1 = *(const bfrag*)&Hb[16 + l16][ks * 32 + lk8];
            #pragma unroll
            for (int ct = 0; ct < 2; ++ct) {
                const bfrag bv = *(const bfrag*)(w2t + (size_t)(n0 + ct * 16 + l16) * 256 + ks * 32 + lk8);
                acc[0][ct] = __builtin_amdgcn_mfma_f32_16x16x32_bf16(a0, bv, acc[0][ct], 0, 0, 0);
                acc[1][ct] = __builtin_amdgcn_mfma_f32_16x16x32_bf16(a1, bv, acc[1][ct], 0, 0, 0);
            }
        }
        #pragma unroll
        for (int ct = 0; ct < 2; ++ct) {
            const float bb = b2[n0 + ct * 16 + l16];
            #pragma unroll
            for (int rt = 0; rt < 2; ++rt)
                #pragma unroll
                for (int r = 0; r < 4; ++r) {
                    const int row = g0 + rt * 16 + l4 + r;
                    const int col = n0 + ct * 16 + l16;
                    errv[rt][ct][r] = emb[(size_t)row * DD + col] - (acc[rt][ct][r] + bb);
                }
        }
    }

    // ================= Phase C: R = relu([X|C] @ Wg1 + bg1)  (32x256, K=256) =================
    {
        const int n0 = wid * 64;
        f32x4 acc[2][4];
        #pragma unroll
        for (int rt = 0; rt < 2; ++rt)
            #pragma unroll
            for (int ct = 0; ct < 4; ++ct) acc[rt][ct] = zf;
        #pragma unroll
        for (int ks = 0; ks < 8; ++ks) {
            const u16 (*Sb)[136] = (ks < 4) ? Xb : Cb;
            const int kk = (ks & 3) * 32 + lk8;
            const bfrag a0 = *(const bfrag*)&Sb[l16][kk];
            const bfrag a1 = *(const bfrag*)&Sb[16 + l16][kk];
            #pragma unroll
            for (int ct = 0; ct < 4; ++ct) {
                const bfrag bv = *(const bfrag*)(wg1t + (size_t)(n0 + ct * 16 + l16) * 256 + ks * 32 + lk8);
                acc[0][ct] = __builtin_amdgcn_mfma_f32_16x16x32_bf16(a0, bv, acc[0][ct], 0, 0, 0);
                acc[1][ct] = __builtin_amdgcn_mfma_f32_16x16x32_bf16(a1, bv, acc[1][ct], 0, 0, 0);
            }
        }
        __syncthreads();   // all waves done reading Hb (phase B) before overwrite
        #pragma unroll
        for (int ct = 0; ct < 4; ++ct) {
            const float bb = bg1[n0 + ct * 16 + l16];
            #pragma unroll
            for (int rt = 0; rt < 2; ++rt)
                #pragma unroll
                for (int r = 0; r < 4; ++r)
                    Hb[rt * 16 + l4 + r][n0 + ct * 16 + l16] = f2bf(fmaxf(acc[rt][ct][r] + bb, 0.f));
        }
    }
    __syncthreads();

    // ================= Phase D: G = R @ Wg2 + bg2 ; out = x + LR*sigmoid(G)*err =================
    {
        const int n0 = wid * 32;
        f32x4 acc[2][2];
        acc[0][0] = zf; acc[0][1] = zf; acc[1][0] = zf; acc[1][1] = zf;
        #pragma unroll
        for (int ks = 0; ks < 8; ++ks) {
            const bfrag a0 = *(const bfrag*)&Hb[l16][ks * 32 + lk8];
            const bfrag a1 = *(const bfrag*)&Hb[16 + l16][ks * 32 + lk8];
            #pragma unroll
            for (int ct = 0; ct < 2; ++ct) {
                const bfrag bv = *(const bfrag*)(wg2t + (size_t)(n0 + ct * 16 + l16) * 256 + ks * 32 + lk8);
                acc[0][ct] = __builtin_amdgcn_mfma_f32_16x16x32_bf16(a0, bv, acc[0][ct], 0, 0, 0);
                acc[1][ct] = __builtin_amdgcn_mfma_f32_16x16x32_bf16(a1, bv, acc[1][ct], 0, 0, 0);
            }
        }
        #pragma unroll
        for (int ct = 0; ct < 2; ++ct) {
            const float bb = bg2[n0 + ct * 16 + l16];
            #pragma unroll
            for (int rt = 0; rt < 2; ++rt)
                #pragma unroll
                for (int r = 0; r < 4; ++r) {
                    const int row = g0 + rt * 16 + l4 + r;
                    const int col = n0 + ct * 16 + l16;
                    const float z = acc[rt][ct][r] + bb;
                    const float gate = 1.f / (1.f + __expf(-z));
                    const float x = cur[(size_t)row * DD + col];
                    outp[(size_t)row * DD + col] = x + LRATE * gate * errv[rt][ct][r];
                }
        }
    }
}

extern "C" void kernel_launch(void* const* d_in, const int* in_sizes, int n_in,
                              void* d_out, int out_size, void* d_ws, size_t ws_size,
                              hipStream_t stream) {
    const float* emb = (const float*)d_in[0];
    const float* W1  = (const float*)d_in[1];
    const float* b1  = (const float*)d_in[2];
    const float* lng = (const float*)d_in[3];
    const float* lnb = (const float*)d_in[4];
    const float* W2  = (const float*)d_in[5];
    const float* b2  = (const float*)d_in[6];
    const float* Wg1 = (const float*)d_in[7];
    const float* bg1 = (const float*)d_in[8];
    const float* Wg2 = (const float*)d_in[9];
    const float* bg2 = (const float*)d_in[10];
    float* out = (float*)d_out;

    u16*   wsw  = (u16*)d_ws;                          // 320 KB bf16 transposed weights
    float* ping = (float*)((char*)d_ws + (1 << 20));   // 64 MB refined scratch

    const u16* w1t  = wsw;
    const u16* w2t  = wsw + 32768;
    const u16* wg1t = wsw + 65536;
    const u16* wg2t = wsw + 131072;

    prep_weights<<<640, 256, 0, stream>>>(W1, W2, Wg1, Wg2, wsw);

    const dim3 grid(NTOK / TM);
    const dim3 block(256);
    // refined chain: emb -> out -> ping -> out -> ping -> out
    refine_iter<<<grid, block, 0, stream>>>(emb,  emb, out,  w1t, w2t, wg1t, wg2t, b1, lng, lnb, b2, bg1, bg2);
    refine_iter<<<grid, block, 0, stream>>>(out,  emb, ping, w1t, w2t, wg1t, wg2t, b1, lng, lnb, b2, bg1, bg2);
    refine_iter<<<grid, block, 0, stream>>>(ping, emb, out,  w1t, w2t, wg1t, wg2t, b1, lng, lnb, b2, bg1, bg2);
    refine_iter<<<grid, block, 0, stream>>>(out,  emb, ping, w1t, w2t, wg1t, wg2t, b1, lng, lnb, b2, bg1, bg2);
    refine_iter<<<grid, block, 0, stream>>>(ping, emb, out,  w1t, w2t, wg1t, wg2t, b1, lng, lnb, b2, bg1, bg2);
}

// Round 5
// 849.808 us; speedup vs baseline: 3.7414x; 1.1735x over previous
//
#include <hip/hip_runtime.h>

#define BB   16
#define SS   8192
#define DD   128
#define HH   256
#define NTOK (BB * SS)
#define TM   32
#define LRATE 0.1f
#define EPSV  1e-5f
#define XST  136   // Xb/Cb stride in shorts (68 dwords; frag reads hit 8-access min)
#define HST  260   // Hb stride in shorts (130 dwords; 4 rows = 520 dwords = +8 banks)

typedef short  bfrag __attribute__((ext_vector_type(8)));   // 8 bf16 = 4 VGPR (MFMA A/B frag)
typedef float  f32x4 __attribute__((ext_vector_type(4)));   // MFMA C/D frag
typedef unsigned short u16;

__device__ __forceinline__ u16 f2bf(float x) {
    unsigned u = __float_as_uint(x);
    unsigned r = (u + 0x7FFFu + ((u >> 16) & 1u)) >> 16;   // RTN-even
    return (u16)r;
}

// ---- weight prep: fp32 [K][N] -> bf16 transposed [N][K] in ws ----
// layout (shorts): W1t[256][128] @0, W2t[128][256] @32768, Wg1t[256][256] @65536, Wg2t[128][256] @131072
__global__ void prep_weights(const float* __restrict__ W1, const float* __restrict__ W2,
                             const float* __restrict__ Wg1, const float* __restrict__ Wg2,
                             u16* __restrict__ wsw) {
    int i = blockIdx.x * 256 + threadIdx.x;   // 0 .. 163839
    if (i < 32768) { int n = i >> 7, k = i & 127; wsw[i] = f2bf(W1[k * 256 + n]); return; }
    i -= 32768;
    if (i < 32768) { int n = i >> 8, k = i & 255; wsw[32768 + n * 256 + k] = f2bf(W2[k * 128 + n]); return; }
    i -= 32768;
    if (i < 65536) { int n = i >> 8, k = i & 255; wsw[65536 + n * 256 + k] = f2bf(Wg1[k * 256 + n]); return; }
    i -= 65536;
    { int n = i >> 8, k = i & 255; wsw[131072 + n * 256 + k] = f2bf(Wg2[k * 128 + n]); }
}

__global__ __launch_bounds__(256, 4)
void refine_iter(const float* __restrict__ cur, const float* __restrict__ emb,
                 float* __restrict__ outp,
                 const u16* __restrict__ w1t, const u16* __restrict__ w2t,
                 const u16* __restrict__ wg1t, const u16* __restrict__ wg2t,
                 const float* __restrict__ b1, const float* __restrict__ lng,
                 const float* __restrict__ lnb, const float* __restrict__ b2,
                 const float* __restrict__ bg1, const float* __restrict__ bg2)
{
    __shared__ u16   Xb[TM][XST];     // refined tokens, bf16
    __shared__ u16   Cb[TM][XST];     // context, bf16
    __shared__ u16   Hb[TM][HST];     // hidden H (phase B input) then R (phase D input)
    __shared__ float red1[TM][4];
    __shared__ float red2[TM][4];
    __shared__ float mu_s[TM];
    __shared__ float rs_s[TM];

    const int t    = threadIdx.x;
    const int g0   = blockIdx.x * TM;
    const int lane = t & 63;
    const int wid  = t >> 6;              // 4 waves
    const int l16  = lane & 15;
    const int lk8  = (lane >> 4) * 8;     // k-offset within a 32-chunk
    const int l4   = (lane >> 4) * 4;     // D-frag row offset

    // ---- stage x tile + context tile (fp32 -> bf16) ----
    #pragma unroll
    for (int k = 0; k < 4; ++k) {
        const int f = t + k * 256;
        const int m = f >> 5;
        const int o = (f & 31) * 4;
        const int gt = g0 + m;
        const int s  = gt & (SS - 1);
        const int rowbase = gt - s;
        const int sp = (s == 0) ? 1 : s - 1;
        const int sn = (s == SS - 1) ? (SS - 2) : s + 1;
        const float4 xv = *(const float4*)(cur + (size_t)gt * DD + o);
        const float4 av = *(const float4*)(cur + (size_t)(rowbase + sp) * DD + o);
        const float4 bv = *(const float4*)(cur + (size_t)(rowbase + sn) * DD + o);
        ushort4 xu; xu.x = f2bf(xv.x); xu.y = f2bf(xv.y); xu.z = f2bf(xv.z); xu.w = f2bf(xv.w);
        *(ushort4*)&Xb[m][o] = xu;
        ushort4 cu;
        cu.x = f2bf(0.5f * (av.x + bv.x)); cu.y = f2bf(0.5f * (av.y + bv.y));
        cu.z = f2bf(0.5f * (av.z + bv.z)); cu.w = f2bf(0.5f * (av.w + bv.w));
        *(ushort4*)&Cb[m][o] = cu;
    }
    __syncthreads();

    const f32x4 zf = {0.f, 0.f, 0.f, 0.f};

    // ================= Phase A: Y1 = X @ W1 + b1  (32x256, K=128) =================
    {
        const int n0 = wid * 64;
        f32x4 acc[2][4];
        #pragma unroll
        for (int rt = 0; rt < 2; ++rt)
            #pragma unroll
            for (int ct = 0; ct < 4; ++ct) acc[rt][ct] = zf;
        #pragma unroll
        for (int ks = 0; ks < 4; ++ks) {
            const bfrag a0 = *(const bfrag*)&Xb[l16][ks * 32 + lk8];
            const bfrag a1 = *(const bfrag*)&Xb[16 + l16][ks * 32 + lk8];
            #pragma unroll
            for (int ct = 0; ct < 4; ++ct) {
                const bfrag bv = *(const bfrag*)(w1t + (size_t)(n0 + ct * 16 + l16) * 128 + ks * 32 + lk8);
                acc[0][ct] = __builtin_amdgcn_mfma_f32_16x16x32_bf16(a0, bv, acc[0][ct], 0, 0, 0);
                acc[1][ct] = __builtin_amdgcn_mfma_f32_16x16x32_bf16(a1, bv, acc[1][ct], 0, 0, 0);
            }
        }
        // add bias before LN stats
        #pragma unroll
        for (int ct = 0; ct < 4; ++ct) {
            const float bb = b1[n0 + ct * 16 + l16];
            #pragma unroll
            for (int rt = 0; rt < 2; ++rt)
                #pragma unroll
                for (int r = 0; r < 4; ++r) acc[rt][ct][r] += bb;
        }

        // ---- LN stats in registers: 16-lane butterfly per (rt,r) row ----
        #pragma unroll
        for (int rt = 0; rt < 2; ++rt)
            #pragma unroll
            for (int r = 0; r < 4; ++r) {
                float a = 0.f, q = 0.f;
                #pragma unroll
                for (int ct = 0; ct < 4; ++ct) {
                    const float v = acc[rt][ct][r];
                    a += v; q += v * v;
                }
                #pragma unroll
                for (int m = 1; m <= 8; m <<= 1) {
                    a += __shfl_xor(a, m);
                    q += __shfl_xor(q, m);
                }
                if (l16 == 0) {
                    const int row = rt * 16 + l4 + r;
                    red1[row][wid] = a;
                    red2[row][wid] = q;
                }
            }
        __syncthreads();
        if (t < TM) {
            const float s1 = red1[t][0] + red1[t][1] + red1[t][2] + red1[t][3];
            const float s2 = red2[t][0] + red2[t][1] + red2[t][2] + red2[t][3];
            const float mu  = s1 * (1.f / (float)HH);
            const float var = s2 * (1.f / (float)HH) - mu * mu;
            mu_s[t] = mu;
            rs_s[t] = rsqrtf(var + EPSV);
        }
        __syncthreads();

        // ---- normalize + affine + relu -> Hb (bf16), direct from registers ----
        #pragma unroll
        for (int ct = 0; ct < 4; ++ct) {
            const int col = n0 + ct * 16 + l16;
            const float g = lng[col];
            const float b = lnb[col];
            #pragma unroll
            for (int rt = 0; rt < 2; ++rt)
                #pragma unroll
                for (int r = 0; r < 4; ++r) {
                    const int row = rt * 16 + l4 + r;
                    const float h = fmaxf((acc[rt][ct][r] - mu_s[row]) * rs_s[row] * g + b, 0.f);
                    Hb[row][col] = f2bf(h);
                }
        }
    }
    __syncthreads();

    // ================= Phase B: P = H @ W2 + b2 ; err = emb - P  (32x128, K=256) =================
    float errv[2][2][4];
    {
        const int n0 = wid * 32;
        f32x4 acc[2][2];
        acc[0][0] = zf; acc[0][1] = zf; acc[1][0] = zf; acc[1][1] = zf;
        #pragma unroll
        for (int ks = 0; ks < 8; ++ks) {
            const bfrag a0 = *(const bfrag*)&Hb[l16][ks * 32 + lk8];
            const bfrag a1 = *(const bfrag*)&Hb[16 + l16][ks * 32 + lk8];
            #pragma unroll
            for (int ct = 0; ct < 2; ++ct) {
                const bfrag bv = *(const bfrag*)(w2t + (size_t)(n0 + ct * 16 + l16) * 256 + ks * 32 + lk8);
                acc[0][ct] = __builtin_amdgcn_mfma_f32_16x16x32_bf16(a0, bv, acc[0][ct], 0, 0, 0);
                acc[1][ct] = __builtin_amdgcn_mfma_f32_16x16x32_bf16(a1, bv, acc[1][ct], 0, 0, 0);
            }
        }
        #pragma unroll
        for (int ct = 0; ct < 2; ++ct) {
            const float bb = b2[n0 + ct * 16 + l16];
            #pragma unroll
            for (int rt = 0; rt < 2; ++rt)
                #pragma unroll
                for (int r = 0; r < 4; ++r) {
                    const int row = g0 + rt * 16 + l4 + r;
                    const int col = n0 + ct * 16 + l16;
                    errv[rt][ct][r] = emb[(size_t)row * DD + col] - (acc[rt][ct][r] + bb);
                }
        }
    }

    // ================= Phase C: R = relu([X|C] @ Wg1 + bg1)  (32x256, K=256) =================
    {
        const int n0 = wid * 64;
        f32x4 acc[2][4];
        #pragma unroll
        for (int rt = 0; rt < 2; ++rt)
            #pragma unroll
            for (int ct = 0; ct < 4; ++ct) acc[rt][ct] = zf;
        #pragma unroll
        for (int ks = 0; ks < 8; ++ks) {
            const u16 (*Sb)[XST] = (ks < 4) ? Xb : Cb;
            const int kk = (ks & 3) * 32 + lk8;
            const bfrag a0 = *(const bfrag*)&Sb[l16][kk];
            const bfrag a1 = *(const bfrag*)&Sb[16 + l16][kk];
            #pragma unroll
            for (int ct = 0; ct < 4; ++ct) {
                const bfrag bv = *(const bfrag*)(wg1t + (size_t)(n0 + ct * 16 + l16) * 256 + ks * 32 + lk8);
                acc[0][ct] = __builtin_amdgcn_mfma_f32_16x16x32_bf16(a0, bv, acc[0][ct], 0, 0, 0);
                acc[1][ct] = __builtin_amdgcn_mfma_f32_16x16x32_bf16(a1, bv, acc[1][ct], 0, 0, 0);
            }
        }
        __syncthreads();   // all waves done reading Hb (phase B) before overwrite
        #pragma unroll
        for (int ct = 0; ct < 4; ++ct) {
            const float bb = bg1[n0 + ct * 16 + l16];
            #pragma unroll
            for (int rt = 0; rt < 2; ++rt)
                #pragma unroll
                for (int r = 0; r < 4; ++r)
                    Hb[rt * 16 + l4 + r][n0 + ct * 16 + l16] = f2bf(fmaxf(acc[rt][ct][r] + bb, 0.f));
        }
    }
    __syncthreads();

    // ================= Phase D: G = R @ Wg2 + bg2 ; out = x + LR*sigmoid(G)*err =================
    {
        const int n0 = wid * 32;
        f32x4 acc[2][2];
        acc[0][0] = zf; acc[0][1] = zf; acc[1][0] = zf; acc[1][1] = zf;
        #pragma unroll
        for (int ks = 0; ks < 8; ++ks) {
            const bfrag a0 = *(const bfrag*)&Hb[l16][ks * 32 + lk8];
            const bfrag a1 = *(const bfrag*)&Hb[16 + l16][ks * 32 + lk8];
            #pragma unroll
            for (int ct = 0; ct < 2; ++ct) {
                const bfrag bv = *(const bfrag*)(wg2t + (size_t)(n0 + ct * 16 + l16) * 256 + ks * 32 + lk8);
                acc[0][ct] = __builtin_amdgcn_mfma_f32_16x16x32_bf16(a0, bv, acc[0][ct], 0, 0, 0);
                acc[1][ct] = __builtin_amdgcn_mfma_f32_16x16x32_bf16(a1, bv, acc[1][ct], 0, 0, 0);
            }
        }
        #pragma unroll
        for (int ct = 0; ct < 2; ++ct) {
            const float bb = bg2[n0 + ct * 16 + l16];
            #pragma unroll
            for (int rt = 0; rt < 2; ++rt)
                #pragma unroll
                for (int r = 0; r < 4; ++r) {
                    const int row = g0 + rt * 16 + l4 + r;
                    const int col = n0 + ct * 16 + l16;
                    const float z = acc[rt][ct][r] + bb;
                    const float gate = 1.f / (1.f + __expf(-z));
                    const float x = cur[(size_t)row * DD + col];
                    outp[(size_t)row * DD + col] = x + LRATE * gate * errv[rt][ct][r];
                }
        }
    }
}

extern "C" void kernel_launch(void* const* d_in, const int* in_sizes, int n_in,
                              void* d_out, int out_size, void* d_ws, size_t ws_size,
                              hipStream_t stream) {
    const float* emb = (const float*)d_in[0];
    const float* W1  = (const float*)d_in[1];
    const float* b1  = (const float*)d_in[2];
    const float* lng = (const float*)d_in[3];
    const float* lnb = (const float*)d_in[4];
    const float* W2  = (const float*)d_in[5];
    const float* b2  = (const float*)d_in[6];
    const float* Wg1 = (const float*)d_in[7];
    const float* bg1 = (const float*)d_in[8];
    const float* Wg2 = (const float*)d_in[9];
    const float* bg2 = (const float*)d_in[10];
    float* out = (float*)d_out;

    u16*   wsw  = (u16*)d_ws;                          // 320 KB bf16 transposed weights
    float* ping = (float*)((char*)d_ws + (1 << 20));   // 64 MB refined scratch

    const u16* w1t  = wsw;
    const u16* w2t  = wsw + 32768;
    const u16* wg1t = wsw + 65536;
    const u16* wg2t = wsw + 131072;

    prep_weights<<<640, 256, 0, stream>>>(W1, W2, Wg1, Wg2, wsw);

    const dim3 grid(NTOK / TM);
    const dim3 block(256);
    // refined chain: emb -> out -> ping -> out -> ping -> out
    refine_iter<<<grid, block, 0, stream>>>(emb,  emb, out,  w1t, w2t, wg1t, wg2t, b1, lng, lnb, b2, bg1, bg2);
    refine_iter<<<grid, block, 0, stream>>>(out,  emb, ping, w1t, w2t, wg1t, wg2t, b1, lng, lnb, b2, bg1, bg2);
    refine_iter<<<grid, block, 0, stream>>>(ping, emb, out,  w1t, w2t, wg1t, wg2t, b1, lng, lnb, b2, bg1, bg2);
    refine_iter<<<grid, block, 0, stream>>>(out,  emb, ping, w1t, w2t, wg1t, wg2t, b1, lng, lnb, b2, bg1, bg2);
    refine_iter<<<grid, block, 0, stream>>>(ping, emb, out,  w1t, w2t, wg1t, wg2t, b1, lng, lnb, b2, bg1, bg2);
}